// Round 4
// baseline (362.640 us; speedup 1.0000x reference)
//
#include <hip/hip_runtime.h>

#define N_NODES 50000
#define D 128
#define N_EDGES 800000

typedef __attribute__((ext_vector_type(8))) short short8;
typedef __attribute__((ext_vector_type(4))) float f32x4;

__device__ __forceinline__ unsigned short f2bf(float f) {
    unsigned u = __builtin_bit_cast(unsigned, f);
    u += 0x7FFFu + ((u >> 16) & 1u);
    return (unsigned short)(u >> 16);
}
__device__ __forceinline__ float bflo(unsigned p) {
    return __builtin_bit_cast(float, p << 16);
}
__device__ __forceinline__ float bfhi(unsigned p) {
    return __builtin_bit_cast(float, p & 0xFFFF0000u);
}

// ---- build wt[s][c][k] bf16 (transposed, c-major) from w[s][k][c] f32 ----
__global__ __launch_bounds__(256) void wt_build(const float* __restrict__ w,
                                                unsigned short* __restrict__ wt) {
    int i = blockIdx.x * 256 + threadIdx.x;
    if (i < 2 * D * D) {
        int s = i >> 14, rem = i & 16383, c = rem >> 7, k = rem & 127;
        wt[i] = f2bf(w[s * D * D + k * D + c]);
    }
}

// ---- dual-support MFMA GEMM: pre_s = bf16(x @ W_s) ----
template<int NS>
__global__ __launch_bounds__(256) void gemm_mfma(const float* __restrict__ x,
                                                 const unsigned short* __restrict__ wt,
                                                 unsigned short* __restrict__ pre0,
                                                 unsigned short* __restrict__ pre1,
                                                 int n_rows) {
    const int lane = threadIdx.x & 63;
    const int wid  = threadIdx.x >> 6;
    const int q    = lane >> 4;
    const int rlo  = lane & 15;
    const int r0   = blockIdx.x * 64 + wid * 16;
    if (r0 >= n_rows) return;

    const float4* x4 = (const float4*)x;
    int arow  = r0 + rlo;
    int arowc = arow < n_rows ? arow : n_rows - 1;

    short8 afr[4];
    #pragma unroll
    for (int kb = 0; kb < 4; ++kb) {
        float4 fa = x4[(size_t)arowc * 32 + kb * 8 + q * 2];
        float4 fb = x4[(size_t)arowc * 32 + kb * 8 + q * 2 + 1];
        short8 a;
        a[0] = (short)f2bf(fa.x); a[1] = (short)f2bf(fa.y);
        a[2] = (short)f2bf(fa.z); a[3] = (short)f2bf(fa.w);
        a[4] = (short)f2bf(fb.x); a[5] = (short)f2bf(fb.y);
        a[6] = (short)f2bf(fb.z); a[7] = (short)f2bf(fb.w);
        afr[kb] = a;
    }

    const short8* wt8 = (const short8*)wt;
    f32x4 acc[NS][8];
    #pragma unroll
    for (int s = 0; s < NS; ++s)
        #pragma unroll
        for (int t = 0; t < 8; ++t)
            acc[s][t] = (f32x4){0.f, 0.f, 0.f, 0.f};

    #pragma unroll
    for (int t = 0; t < 8; ++t) {
        int c = t * 16 + rlo;
        #pragma unroll
        for (int kb = 0; kb < 4; ++kb) {
            short8 b0 = wt8[(size_t)c * 16 + kb * 4 + q];
            acc[0][t] = __builtin_amdgcn_mfma_f32_16x16x32_bf16(afr[kb], b0, acc[0][t], 0, 0, 0);
            if (NS == 2) {
                short8 b1 = wt8[(size_t)(D + c) * 16 + kb * 4 + q];
                acc[1][t] = __builtin_amdgcn_mfma_f32_16x16x32_bf16(afr[kb], b1, acc[1][t], 0, 0, 0);
            }
        }
    }

    #pragma unroll
    for (int i = 0; i < 4; ++i) {
        int rw = r0 + q * 4 + i;
        if (rw < n_rows) {
            #pragma unroll
            for (int t = 0; t < 8; ++t) {
                pre0[(size_t)rw * D + t * 16 + rlo] = f2bf(acc[0][t][i]);
                if (NS == 2) pre1[(size_t)rw * D + t * 16 + rlo] = f2bf(acc[1][t][i]);
            }
        }
    }
}

// ---- CSR build: histogram (y-dim = support) ----
__global__ __launch_bounds__(256) void hist2(const int* __restrict__ r0,
                                             const int* __restrict__ r1,
                                             int* __restrict__ cnt, int n_edges) {
    const int* r = blockIdx.y ? r1 : r0;
    int* c = cnt + blockIdx.y * N_NODES;
    for (int e = blockIdx.x * 256 + threadIdx.x; e < n_edges; e += gridDim.x * 256)
        atomicAdd(&c[r[e]], 1);
}

// ---- single-block-per-support exclusive scan; also seeds cur = offsets ----
__global__ __launch_bounds__(1024) void scan2(const int* __restrict__ counts_base,
                                              int* __restrict__ offsets_base,
                                              int* __restrict__ cur_base, int n) {
    const int* counts = counts_base + blockIdx.x * n;
    int* offsets      = offsets_base + blockIdx.x * (n + 1);
    int* cur          = cur_base + blockIdx.x * n;
    __shared__ int wsum[16];
    __shared__ int carry_s;
    const int lane = threadIdx.x & 63;
    const int wid  = threadIdx.x >> 6;
    if (threadIdx.x == 0) carry_s = 0;
    __syncthreads();
    for (int base = 0; base < n; base += 1024) {
        int i = base + (int)threadIdx.x;
        int v = (i < n) ? counts[i] : 0;
        int incl = v;
        #pragma unroll
        for (int off = 1; off < 64; off <<= 1) {
            int t = __shfl_up(incl, off);
            if (lane >= off) incl += t;
        }
        if (lane == 63) wsum[wid] = incl;
        __syncthreads();
        int carry = carry_s;
        if (wid == 0 && lane < 16) {
            int wv = wsum[lane];
            int winc = wv;
            #pragma unroll
            for (int off = 1; off < 16; off <<= 1) {
                int t = __shfl_up(winc, off);
                if (lane >= off) winc += t;
            }
            wsum[lane] = winc - wv;
        }
        __syncthreads();
        int excl = carry + wsum[wid] + (incl - v);
        if (i < n) { offsets[i] = excl; cur[i] = excl; }
        __syncthreads();
        if (threadIdx.x == 1023) carry_s = excl + v;
        __syncthreads();
    }
    if (threadIdx.x == 0) offsets[n] = carry_s;
}

// ---- CSR fill: single packed 8B record per edge (y-dim = support) ----
__global__ __launch_bounds__(256) void fill2(const int* __restrict__ r0, const int* __restrict__ c0,
                                             const float* __restrict__ v0,
                                             const int* __restrict__ r1, const int* __restrict__ c1,
                                             const float* __restrict__ v1,
                                             int* __restrict__ cur_base,
                                             int2* __restrict__ ep_base, int n_edges) {
    int s = blockIdx.y;
    const int*   r = s ? r1 : r0;
    const int*   c = s ? c1 : c0;
    const float* v = s ? v1 : v0;
    int*  cu = cur_base + s * N_NODES;
    int2* ep = ep_base + (size_t)s * N_EDGES;
    for (int e = blockIdx.x * 256 + threadIdx.x; e < n_edges; e += gridDim.x * 256) {
        int rr = r[e];
        int p = atomicAdd(&cu[rr], 1);
        int2 rec;
        rec.x = c[e];
        rec.y = __float_as_int(v[e]);
        ep[p] = rec;
    }
}

// ---- row accumulate over one CSR (bf16 pre, packed records) ----
__device__ __forceinline__ void row_acc(const int2* __restrict__ ep,
                                        const unsigned short* __restrict__ pre,
                                        int b, int e, int lane, float& ax, float& ay) {
    int i = b;
    for (; i + 3 < e; i += 4) {
        int2 e0 = ep[i], e1 = ep[i+1], e2 = ep[i+2], e3 = ep[i+3];
        unsigned p0 = *(const unsigned*)(pre + (size_t)e0.x * D + 2 * lane);
        unsigned p1 = *(const unsigned*)(pre + (size_t)e1.x * D + 2 * lane);
        unsigned p2 = *(const unsigned*)(pre + (size_t)e2.x * D + 2 * lane);
        unsigned p3 = *(const unsigned*)(pre + (size_t)e3.x * D + 2 * lane);
        float w0 = __int_as_float(e0.y), w1 = __int_as_float(e1.y);
        float w2 = __int_as_float(e2.y), w3 = __int_as_float(e3.y);
        ax = fmaf(w0, bflo(p0), ax); ay = fmaf(w0, bfhi(p0), ay);
        ax = fmaf(w1, bflo(p1), ax); ay = fmaf(w1, bfhi(p1), ay);
        ax = fmaf(w2, bflo(p2), ax); ay = fmaf(w2, bfhi(p2), ay);
        ax = fmaf(w3, bflo(p3), ax); ay = fmaf(w3, bfhi(p3), ay);
    }
    for (; i < e; ++i) {
        int2 e0 = ep[i];
        float w = __int_as_float(e0.y);
        unsigned p = *(const unsigned*)(pre + (size_t)e0.x * D + 2 * lane);
        ax = fmaf(w, bflo(p), ax); ay = fmaf(w, bfhi(p), ay);
    }
}

// ---- fused gather: out = relu(A0@pre0 + A1@pre1), one wave per row ----
__global__ __launch_bounds__(256) void gather_fused(const int* __restrict__ off_base,
                                                    const int2* __restrict__ ep_base,
                                                    const unsigned short* __restrict__ pre0,
                                                    const unsigned short* __restrict__ pre1,
                                                    float* __restrict__ out, int n_rows) {
    const int lane = threadIdx.x & 63;
    const int wid  = threadIdx.x >> 6;
    const int wpg  = 4 * gridDim.x;
    float2* out2 = (float2*)out;
    for (int r = blockIdx.x * 4 + wid; r < n_rows; r += wpg) {
        float ax0 = 0.f, ay0 = 0.f, ax1 = 0.f, ay1 = 0.f;
        row_acc(ep_base, pre0, off_base[r], off_base[r + 1], lane, ax0, ay0);
        const int* o1 = off_base + (N_NODES + 1);
        row_acc(ep_base + N_EDGES, pre1, o1[r], o1[r + 1], lane, ax1, ay1);
        float2 o;
        o.x = fmaxf(ax0 + ax1, 0.f);
        o.y = fmaxf(ay0 + ay1, 0.f);
        out2[(size_t)r * 64 + lane] = o;
    }
}

// ---- single-support gather (sequential fallback) ----
template<int ACCUM_RELU>
__global__ __launch_bounds__(256) void gather_one(const int* __restrict__ off,
                                                  const int2* __restrict__ ep,
                                                  const unsigned short* __restrict__ pre,
                                                  float* __restrict__ out, int n_rows) {
    const int lane = threadIdx.x & 63;
    const int wid  = threadIdx.x >> 6;
    const int wpg  = 4 * gridDim.x;
    float2* out2 = (float2*)out;
    for (int r = blockIdx.x * 4 + wid; r < n_rows; r += wpg) {
        float ax = 0.f, ay = 0.f;
        row_acc(ep, pre, off[r], off[r + 1], lane, ax, ay);
        float2 o;
        if (ACCUM_RELU) {
            float2 prev = out2[(size_t)r * 64 + lane];
            o.x = fmaxf(prev.x + ax, 0.f);
            o.y = fmaxf(prev.y + ay, 0.f);
        } else {
            o.x = ax; o.y = ay;
        }
        out2[(size_t)r * 64 + lane] = o;
    }
}

extern "C" void kernel_launch(void* const* d_in, const int* in_sizes, int n_in,
                              void* d_out, int out_size, void* d_ws, size_t ws_size,
                              hipStream_t stream) {
    const float* x       = (const float*)d_in[0];
    const float* weights = (const float*)d_in[1];
    const int*   ei0     = (const int*)d_in[2];
    const float* v0      = (const float*)d_in[3];
    const int*   ei1     = (const int*)d_in[4];
    const float* v1      = (const float*)d_in[5];
    float* out = (float*)d_out;

    dim3 blk(256);
    const size_t PRE_B = (size_t)N_NODES * D * sizeof(unsigned short);  // 12.8 MB
    const size_t WT_B  = (size_t)2 * D * D * sizeof(unsigned short);    // 64 KB

    char* wsb = (char*)d_ws;
    size_t need_full = PRE_B * 2 + WT_B + (size_t)(2 * (N_NODES + 1) + 4 * N_NODES) * 4
                     + (size_t)2 * N_EDGES * sizeof(int2);

    if (ws_size >= need_full) {
        unsigned short* pre0 = (unsigned short*)wsb;
        unsigned short* pre1 = (unsigned short*)(wsb + PRE_B);
        unsigned short* wt   = (unsigned short*)(wsb + 2 * PRE_B);
        int*  off = (int*)(wsb + 2 * PRE_B + WT_B);
        int*  cnt = off + 2 * (N_NODES + 1);
        int*  cur = cnt + 2 * N_NODES;
        int2* ep  = (int2*)(cur + 2 * N_NODES);

        hipMemsetAsync(cnt, 0, (size_t)2 * N_NODES * sizeof(int), stream);
        wt_build<<<128, blk, 0, stream>>>(weights, wt);
        hist2<<<dim3(1024, 2), blk, 0, stream>>>(ei0, ei1, cnt, N_EDGES);
        scan2<<<2, 1024, 0, stream>>>(cnt, off, cur, N_NODES);
        fill2<<<dim3(1024, 2), blk, 0, stream>>>(ei0, ei0 + N_EDGES, v0,
                                                 ei1, ei1 + N_EDGES, v1,
                                                 cur, ep, N_EDGES);
        gemm_mfma<2><<<(N_NODES + 63) / 64, blk, 0, stream>>>(x, wt, pre0, pre1, N_NODES);
        gather_fused<<<12500, blk, 0, stream>>>(off, ep, pre0, pre1, out, N_NODES);
    } else {
        unsigned short* pre = (unsigned short*)wsb;
        unsigned short* wt  = (unsigned short*)(wsb + PRE_B);
        int*  off = (int*)(wsb + PRE_B + WT_B);
        int*  cnt = off + (N_NODES + 1);
        int*  cur = cnt + N_NODES;
        int2* ep  = (int2*)(cur + N_NODES);

        wt_build<<<128, blk, 0, stream>>>(weights, wt);
        const int* rows[2] = {ei0, ei1};
        const int* cols[2] = {ei0 + N_EDGES, ei1 + N_EDGES};
        const float* vals[2] = {v0, v1};
        for (int s = 0; s < 2; ++s) {
            hipMemsetAsync(cnt, 0, (size_t)N_NODES * sizeof(int), stream);
            hist2<<<dim3(1024, 1), blk, 0, stream>>>(rows[s], rows[s], cnt, N_EDGES);
            scan2<<<1, 1024, 0, stream>>>(cnt, off, cur, N_NODES);
            fill2<<<dim3(1024, 1), blk, 0, stream>>>(rows[s], cols[s], vals[s],
                                                     rows[s], cols[s], vals[s],
                                                     cur, ep, N_EDGES);
            gemm_mfma<1><<<(N_NODES + 63) / 64, blk, 0, stream>>>(
                x, wt + (size_t)s * D * D, pre, pre, N_NODES);
            if (s == 0)
                gather_one<0><<<12500, blk, 0, stream>>>(off, ep, pre, out, N_NODES);
            else
                gather_one<1><<<12500, blk, 0, stream>>>(off, ep, pre, out, N_NODES);
        }
    }
}

// Round 5
// 262.388 us; speedup vs baseline: 1.3821x; 1.3821x over previous
//
#include <hip/hip_runtime.h>

#define N_NODES 50000
#define D 128
#define N_EDGES 800000

typedef __attribute__((ext_vector_type(8))) short short8;
typedef __attribute__((ext_vector_type(4))) float f32x4;

__device__ __forceinline__ unsigned short f2bf(float f) {
    unsigned u = __builtin_bit_cast(unsigned, f);
    u += 0x7FFFu + ((u >> 16) & 1u);
    return (unsigned short)(u >> 16);
}
__device__ __forceinline__ float bflo(unsigned p) {
    return __builtin_bit_cast(float, p << 16);
}
__device__ __forceinline__ float bfhi(unsigned p) {
    return __builtin_bit_cast(float, p & 0xFFFF0000u);
}

// ---- build wt[s][c][k] bf16 (transposed, c-major) from w[s][k][c] f32 ----
__global__ __launch_bounds__(256) void wt_build(const float* __restrict__ w,
                                                unsigned short* __restrict__ wt) {
    int i = blockIdx.x * 256 + threadIdx.x;
    if (i < 2 * D * D) {
        int s = i >> 14, rem = i & 16383, c = rem >> 7, k = rem & 127;
        wt[i] = f2bf(w[s * D * D + k * D + c]);
    }
}

// ---- dual-support MFMA GEMM: pre_s = bf16(x @ W_s) ----
template<int NS>
__global__ __launch_bounds__(256) void gemm_mfma(const float* __restrict__ x,
                                                 const unsigned short* __restrict__ wt,
                                                 unsigned short* __restrict__ pre0,
                                                 unsigned short* __restrict__ pre1,
                                                 int n_rows) {
    const int lane = threadIdx.x & 63;
    const int wid  = threadIdx.x >> 6;
    const int q    = lane >> 4;
    const int rlo  = lane & 15;
    const int r0   = blockIdx.x * 64 + wid * 16;
    if (r0 >= n_rows) return;

    const float4* x4 = (const float4*)x;
    int arow  = r0 + rlo;
    int arowc = arow < n_rows ? arow : n_rows - 1;

    short8 afr[4];
    #pragma unroll
    for (int kb = 0; kb < 4; ++kb) {
        float4 fa = x4[(size_t)arowc * 32 + kb * 8 + q * 2];
        float4 fb = x4[(size_t)arowc * 32 + kb * 8 + q * 2 + 1];
        short8 a;
        a[0] = (short)f2bf(fa.x); a[1] = (short)f2bf(fa.y);
        a[2] = (short)f2bf(fa.z); a[3] = (short)f2bf(fa.w);
        a[4] = (short)f2bf(fb.x); a[5] = (short)f2bf(fb.y);
        a[6] = (short)f2bf(fb.z); a[7] = (short)f2bf(fb.w);
        afr[kb] = a;
    }

    const short8* wt8 = (const short8*)wt;
    f32x4 acc[NS][8];
    #pragma unroll
    for (int s = 0; s < NS; ++s)
        #pragma unroll
        for (int t = 0; t < 8; ++t)
            acc[s][t] = (f32x4){0.f, 0.f, 0.f, 0.f};

    #pragma unroll
    for (int t = 0; t < 8; ++t) {
        int c = t * 16 + rlo;
        #pragma unroll
        for (int kb = 0; kb < 4; ++kb) {
            short8 b0 = wt8[(size_t)c * 16 + kb * 4 + q];
            acc[0][t] = __builtin_amdgcn_mfma_f32_16x16x32_bf16(afr[kb], b0, acc[0][t], 0, 0, 0);
            if (NS == 2) {
                short8 b1 = wt8[(size_t)(D + c) * 16 + kb * 4 + q];
                acc[1][t] = __builtin_amdgcn_mfma_f32_16x16x32_bf16(afr[kb], b1, acc[1][t], 0, 0, 0);
            }
        }
    }

    #pragma unroll
    for (int i = 0; i < 4; ++i) {
        int rw = r0 + q * 4 + i;
        if (rw < n_rows) {
            #pragma unroll
            for (int t = 0; t < 8; ++t) {
                pre0[(size_t)rw * D + t * 16 + rlo] = f2bf(acc[0][t][i]);
                if (NS == 2) pre1[(size_t)rw * D + t * 16 + rlo] = f2bf(acc[1][t][i]);
            }
        }
    }
}

// ---- histogram + per-edge rank (y-dim = support) ----
// rank[e] = position of edge e among same-row edges (atomic order); coalesced store.
__global__ __launch_bounds__(256) void hist_rank(const int* __restrict__ r0,
                                                 const int* __restrict__ r1,
                                                 int* __restrict__ cnt_base,
                                                 int* __restrict__ rank_base, int n_edges) {
    int s = blockIdx.y;
    const int* r = s ? r1 : r0;
    int* cnt  = cnt_base + s * N_NODES;
    int* rank = rank_base + (size_t)s * N_EDGES;
    for (int e = blockIdx.x * 256 + threadIdx.x; e < n_edges; e += gridDim.x * 256)
        rank[e] = atomicAdd(&cnt[r[e]], 1);
}

// ---- single-block-per-support exclusive scan ----
__global__ __launch_bounds__(1024) void scan2(const int* __restrict__ counts_base,
                                              int* __restrict__ offsets_base, int n) {
    const int* counts = counts_base + blockIdx.x * n;
    int* offsets      = offsets_base + blockIdx.x * (n + 1);
    __shared__ int wsum[16];
    __shared__ int carry_s;
    const int lane = threadIdx.x & 63;
    const int wid  = threadIdx.x >> 6;
    if (threadIdx.x == 0) carry_s = 0;
    __syncthreads();
    for (int base = 0; base < n; base += 1024) {
        int i = base + (int)threadIdx.x;
        int v = (i < n) ? counts[i] : 0;
        int incl = v;
        #pragma unroll
        for (int off = 1; off < 64; off <<= 1) {
            int t = __shfl_up(incl, off);
            if (lane >= off) incl += t;
        }
        if (lane == 63) wsum[wid] = incl;
        __syncthreads();
        int carry = carry_s;
        if (wid == 0 && lane < 16) {
            int wv = wsum[lane];
            int winc = wv;
            #pragma unroll
            for (int off = 1; off < 16; off <<= 1) {
                int t = __shfl_up(winc, off);
                if (lane >= off) winc += t;
            }
            wsum[lane] = winc - wv;
        }
        __syncthreads();
        int excl = carry + wsum[wid] + (incl - v);
        if (i < n) offsets[i] = excl;
        __syncthreads();
        if (threadIdx.x == 1023) carry_s = excl + v;
        __syncthreads();
    }
    if (threadIdx.x == 0) offsets[n] = carry_s;
}

// ---- CSR scatter: no atomics, fire-and-forget 8B stores (y-dim = support) ----
__global__ __launch_bounds__(256) void scatter_csr(const int* __restrict__ r0, const int* __restrict__ c0,
                                                   const float* __restrict__ v0,
                                                   const int* __restrict__ r1, const int* __restrict__ c1,
                                                   const float* __restrict__ v1,
                                                   const int* __restrict__ off_base,
                                                   const int* __restrict__ rank_base,
                                                   int2* __restrict__ ep_base, int n_edges) {
    int s = blockIdx.y;
    const int*   r    = s ? r1 : r0;
    const int*   c    = s ? c1 : c0;
    const float* v    = s ? v1 : v0;
    const int*   off  = off_base + s * (N_NODES + 1);
    const int*   rank = rank_base + (size_t)s * N_EDGES;
    int2* ep = ep_base + (size_t)s * N_EDGES;
    for (int e = blockIdx.x * 256 + threadIdx.x; e < n_edges; e += gridDim.x * 256) {
        int p = off[r[e]] + rank[e];
        int2 rec;
        rec.x = c[e];
        rec.y = __float_as_int(v[e]);
        ep[p] = rec;
    }
}

// ---- row accumulate over one CSR (bf16 pre, packed records) ----
__device__ __forceinline__ void row_acc(const int2* __restrict__ ep,
                                        const unsigned short* __restrict__ pre,
                                        int b, int e, int lane, float& ax, float& ay) {
    int i = b;
    for (; i + 3 < e; i += 4) {
        int2 e0 = ep[i], e1 = ep[i+1], e2 = ep[i+2], e3 = ep[i+3];
        unsigned p0 = *(const unsigned*)(pre + (size_t)e0.x * D + 2 * lane);
        unsigned p1 = *(const unsigned*)(pre + (size_t)e1.x * D + 2 * lane);
        unsigned p2 = *(const unsigned*)(pre + (size_t)e2.x * D + 2 * lane);
        unsigned p3 = *(const unsigned*)(pre + (size_t)e3.x * D + 2 * lane);
        float w0 = __int_as_float(e0.y), w1 = __int_as_float(e1.y);
        float w2 = __int_as_float(e2.y), w3 = __int_as_float(e3.y);
        ax = fmaf(w0, bflo(p0), ax); ay = fmaf(w0, bfhi(p0), ay);
        ax = fmaf(w1, bflo(p1), ax); ay = fmaf(w1, bfhi(p1), ay);
        ax = fmaf(w2, bflo(p2), ax); ay = fmaf(w2, bfhi(p2), ay);
        ax = fmaf(w3, bflo(p3), ax); ay = fmaf(w3, bfhi(p3), ay);
    }
    for (; i < e; ++i) {
        int2 e0 = ep[i];
        float w = __int_as_float(e0.y);
        unsigned p = *(const unsigned*)(pre + (size_t)e0.x * D + 2 * lane);
        ax = fmaf(w, bflo(p), ax); ay = fmaf(w, bfhi(p), ay);
    }
}

// ---- fused gather: out = relu(A0@pre0 + A1@pre1), one wave per row ----
__global__ __launch_bounds__(256) void gather_fused(const int* __restrict__ off_base,
                                                    const int2* __restrict__ ep_base,
                                                    const unsigned short* __restrict__ pre0,
                                                    const unsigned short* __restrict__ pre1,
                                                    float* __restrict__ out, int n_rows) {
    const int lane = threadIdx.x & 63;
    const int wid  = threadIdx.x >> 6;
    const int wpg  = 4 * gridDim.x;
    float2* out2 = (float2*)out;
    for (int r = blockIdx.x * 4 + wid; r < n_rows; r += wpg) {
        float ax0 = 0.f, ay0 = 0.f, ax1 = 0.f, ay1 = 0.f;
        row_acc(ep_base, pre0, off_base[r], off_base[r + 1], lane, ax0, ay0);
        const int* o1 = off_base + (N_NODES + 1);
        row_acc(ep_base + N_EDGES, pre1, o1[r], o1[r + 1], lane, ax1, ay1);
        float2 o;
        o.x = fmaxf(ax0 + ax1, 0.f);
        o.y = fmaxf(ay0 + ay1, 0.f);
        out2[(size_t)r * 64 + lane] = o;
    }
}

// ---- single-support gather (sequential fallback) ----
template<int ACCUM_RELU>
__global__ __launch_bounds__(256) void gather_one(const int* __restrict__ off,
                                                  const int2* __restrict__ ep,
                                                  const unsigned short* __restrict__ pre,
                                                  float* __restrict__ out, int n_rows) {
    const int lane = threadIdx.x & 63;
    const int wid  = threadIdx.x >> 6;
    const int wpg  = 4 * gridDim.x;
    float2* out2 = (float2*)out;
    for (int r = blockIdx.x * 4 + wid; r < n_rows; r += wpg) {
        float ax = 0.f, ay = 0.f;
        row_acc(ep, pre, off[r], off[r + 1], lane, ax, ay);
        float2 o;
        if (ACCUM_RELU) {
            float2 prev = out2[(size_t)r * 64 + lane];
            o.x = fmaxf(prev.x + ax, 0.f);
            o.y = fmaxf(prev.y + ay, 0.f);
        } else {
            o.x = ax; o.y = ay;
        }
        out2[(size_t)r * 64 + lane] = o;
    }
}

extern "C" void kernel_launch(void* const* d_in, const int* in_sizes, int n_in,
                              void* d_out, int out_size, void* d_ws, size_t ws_size,
                              hipStream_t stream) {
    const float* x       = (const float*)d_in[0];
    const float* weights = (const float*)d_in[1];
    const int*   ei0     = (const int*)d_in[2];
    const float* v0      = (const float*)d_in[3];
    const int*   ei1     = (const int*)d_in[4];
    const float* v1      = (const float*)d_in[5];
    float* out = (float*)d_out;

    dim3 blk(256);
    const size_t PRE_B = (size_t)N_NODES * D * sizeof(unsigned short);  // 12.8 MB
    const size_t WT_B  = (size_t)2 * D * D * sizeof(unsigned short);    // 64 KB

    char* wsb = (char*)d_ws;
    size_t need_full = PRE_B * 2 + WT_B + (size_t)(2 * (N_NODES + 1) + 2 * N_NODES) * 4
                     + (size_t)2 * N_EDGES * sizeof(int2);

    if (ws_size >= need_full) {
        unsigned short* pre0 = (unsigned short*)wsb;
        unsigned short* pre1 = (unsigned short*)(wsb + PRE_B);
        unsigned short* wt   = (unsigned short*)(wsb + 2 * PRE_B);
        int*  off = (int*)(wsb + 2 * PRE_B + WT_B);
        int*  cnt = off + 2 * (N_NODES + 1);
        int2* ep  = (int2*)(cnt + 2 * N_NODES);
        // rank[2E] (6.4 MB) aliases pre0 (12.8 MB): scatter_csr completes before
        // gemm_mfma writes pre0 (stream-ordered).
        int*  rank = (int*)pre0;

        hipMemsetAsync(cnt, 0, (size_t)2 * N_NODES * sizeof(int), stream);
        wt_build<<<128, blk, 0, stream>>>(weights, wt);
        hist_rank<<<dim3(1024, 2), blk, 0, stream>>>(ei0, ei1, cnt, rank, N_EDGES);
        scan2<<<2, 1024, 0, stream>>>(cnt, off, N_NODES);
        scatter_csr<<<dim3(1024, 2), blk, 0, stream>>>(ei0, ei0 + N_EDGES, v0,
                                                       ei1, ei1 + N_EDGES, v1,
                                                       off, rank, ep, N_EDGES);
        gemm_mfma<2><<<(N_NODES + 63) / 64, blk, 0, stream>>>(x, wt, pre0, pre1, N_NODES);
        gather_fused<<<12500, blk, 0, stream>>>(off, ep, pre0, pre1, out, N_NODES);
    } else {
        unsigned short* pre = (unsigned short*)wsb;
        unsigned short* wt  = (unsigned short*)(wsb + PRE_B);
        int*  off = (int*)(wsb + PRE_B + WT_B);
        int*  cnt = off + (N_NODES + 1);
        int2* ep  = (int2*)(cnt + N_NODES);
        int*  rank = (int*)pre;   // aliases pre; scatter completes before gemm

        wt_build<<<128, blk, 0, stream>>>(weights, wt);
        const int* rows[2] = {ei0, ei1};
        const int* cols[2] = {ei0 + N_EDGES, ei1 + N_EDGES};
        const float* vals[2] = {v0, v1};
        for (int s = 0; s < 2; ++s) {
            hipMemsetAsync(cnt, 0, (size_t)N_NODES * sizeof(int), stream);
            hist_rank<<<dim3(1024, 1), blk, 0, stream>>>(rows[s], rows[s], cnt, rank, N_EDGES);
            scan2<<<1, 1024, 0, stream>>>(cnt, off, N_NODES);
            scatter_csr<<<dim3(1024, 1), blk, 0, stream>>>(rows[s], cols[s], vals[s],
                                                           rows[s], cols[s], vals[s],
                                                           off, rank, ep, N_EDGES);
            gemm_mfma<1><<<(N_NODES + 63) / 64, blk, 0, stream>>>(
                x, wt + (size_t)s * D * D, pre, pre, N_NODES);
            if (s == 0)
                gather_one<0><<<12500, blk, 0, stream>>>(off, ep, pre, out, N_NODES);
            else
                gather_one<1><<<12500, blk, 0, stream>>>(off, ep, pre, out, N_NODES);
        }
    }
}